// Round 18
// baseline (389.537 us; speedup 1.0000x reference)
//
#include <hip/hip_runtime.h>

#define NBLK 256

typedef float f2 __attribute__((ext_vector_type(2)));   // VGPR pair -> VOP3P v_pk_* f32
typedef float f4 __attribute__((ext_vector_type(4)));

static __device__ __forceinline__ f2 pk_fma(f2 a, f2 b, f2 c) {
#if __has_builtin(__builtin_elementwise_fma)
    return __builtin_elementwise_fma(a, b, c);
#else
    f2 r; r.x = fmaf(a.x, b.x, c.x); r.y = fmaf(a.y, b.y, c.y); return r;
#endif
}

// packed tanh(z) and 1-tanh^2: tanh = 1 - 2/(exp2(2*log2e*z)+1). abs err ~3e-7.
__device__ __forceinline__ void tanh2(const f2 z, f2& th, f2& om) {
    const f2 zz = z * 2.88539008f;
    f2 s;
    s.x = __builtin_amdgcn_rcpf(__builtin_amdgcn_exp2f(zz.x) + 1.0f);
    s.y = __builtin_amdgcn_rcpf(__builtin_amdgcn_exp2f(zz.y) + 1.0f);
    th = 1.0f - 2.0f * s;
    om = 1.0f - th * th;
}

__global__ __launch_bounds__(NBLK, 2) void pinn_kernel(
    const float* __restrict__ T,
    const float* __restrict__ W1, const float* __restrict__ b1,
    const float* __restrict__ W2, const float* __restrict__ b2,
    const float* __restrict__ W3, const float* __restrict__ b3,
    const float* __restrict__ W4, const float* __restrict__ b4,
    const float* __restrict__ Wo, const float* __restrict__ bo,
    const float* __restrict__ C1, const float* __restrict__ C2, const float* __restrict__ C3,
    float* __restrict__ out, int n)
{
    // R15's dual-pipe weight delivery (best measured): even-k rows via s_load (SMEM),
    // odd-k rows via LDS broadcast. NEW: 2 points/lane in ONE pass — launch_bounds
    // min-waves=2 allows 256 VGPR so the compiler cannot j/point-split and re-stream
    // weights (R11's VGPR=112 showed it did). Per-point traffic on BOTH pipes halves.
    __shared__ f4 sOdd[3][10][5];        // odd rows k=2r+1 of W2..W4: 2400 B

    {
        const int u = threadIdx.x;
        if (u < 150) {
            const int L = u / 50, rem = u % 50, r = rem / 5, q = rem % 5;
            const float* WPx = (L == 0) ? W2 : (L == 1) ? W3 : W4;
            sOdd[L][r][q] = *reinterpret_cast<const f4*>(WPx + (2 * r + 1) * 20 + 4 * q);
        }
    }
    __syncthreads();

    const int i0 = blockIdx.x * NBLK + threadIdx.x;
    const int p0 = i0 * 2;
    const int pc = (p0 + 1 < n) ? p0 : (n - 2);     // clamped load base (n >= 2)
    const float2 tt = *reinterpret_cast<const float2*>(T + pc);
    const f2 tA = {tt.x, tt.x};
    const f2 tB = {tt.y, tt.y};

    // State as j-pairs per point: H*[jj] = (h[2jj], h[2jj+1]).
    f2 HA[10], HB[10], DA[10], DB[10];

    // ---- layer 1: z = t*W1 + b1, dz = W1 (tangent dt = 1); SMEM (small) ----
#pragma unroll
    for (int jj = 0; jj < 10; ++jj) {
        const f2 w = *reinterpret_cast<const f2*>(W1 + 2 * jj);
        const f2 b = *reinterpret_cast<const f2*>(b1 + 2 * jj);
        f2 th, om;
        tanh2(pk_fma(tA, w, b), th, om);
        HA[jj] = th;  DA[jj] = om * w;
        tanh2(pk_fma(tB, w, b), th, om);
        HB[jj] = th;  DB[jj] = om * w;
    }

    // ---- layers 2..4: per (k,q) ONE f4 weight feeds 8 pk_fma (2 pts x 2 streams x 2 jj) ----
#define LAYER(LIDX, WP, BP) do {                                                \
        f2 AA[10], AB[10], DDA[10], DDB[10];                                    \
        _Pragma("unroll")                                                       \
        for (int jj = 0; jj < 10; ++jj) {                                       \
            const f2 b = *reinterpret_cast<const f2*>(BP + 2 * jj);             \
            AA[jj] = b;  AB[jj] = b;                                            \
            DDA[jj] = (f2){0.0f, 0.0f};                                         \
            DDB[jj] = (f2){0.0f, 0.0f};                                         \
        }                                                                       \
        _Pragma("unroll")                                                       \
        for (int k = 0; k < 20; ++k) {                                          \
            const float hkA = (k & 1) ? HA[k >> 1].y : HA[k >> 1].x;            \
            const float dkA = (k & 1) ? DA[k >> 1].y : DA[k >> 1].x;            \
            const float hkB = (k & 1) ? HB[k >> 1].y : HB[k >> 1].x;            \
            const float dkB = (k & 1) ? DB[k >> 1].y : DB[k >> 1].x;            \
            const f2 hA2 = {hkA, hkA}, dA2 = {dkA, dkA};                        \
            const f2 hB2 = {hkB, hkB}, dB2 = {dkB, dkB};                        \
            _Pragma("unroll")                                                   \
            for (int q = 0; q < 5; ++q) {                                       \
                const f4 w4 = (k & 1)                                           \
                    ? sOdd[LIDX][k >> 1][q]                                     \
                    : *reinterpret_cast<const f4*>(WP + k * 20 + 4 * q);        \
                const f2 wa = {w4.x, w4.y}, wb = {w4.z, w4.w};                  \
                AA[2*q]    = pk_fma(hA2, wa, AA[2*q]);                          \
                AA[2*q+1]  = pk_fma(hA2, wb, AA[2*q+1]);                        \
                DDA[2*q]   = pk_fma(dA2, wa, DDA[2*q]);                         \
                DDA[2*q+1] = pk_fma(dA2, wb, DDA[2*q+1]);                       \
                AB[2*q]    = pk_fma(hB2, wa, AB[2*q]);                          \
                AB[2*q+1]  = pk_fma(hB2, wb, AB[2*q+1]);                        \
                DDB[2*q]   = pk_fma(dB2, wa, DDB[2*q]);                         \
                DDB[2*q+1] = pk_fma(dB2, wb, DDB[2*q+1]);                       \
            }                                                                   \
        }                                                                       \
        _Pragma("unroll")                                                       \
        for (int jj = 0; jj < 10; ++jj) {                                       \
            f2 th, om;                                                          \
            tanh2(AA[jj], th, om);                                              \
            HA[jj] = th;  DA[jj] = om * DDA[jj];                                \
            tanh2(AB[jj], th, om);                                              \
            HB[jj] = th;  DB[jj] = om * DDB[jj];                                \
        }                                                                       \
    } while (0)

    LAYER(0, W2, b2);
    LAYER(1, W3, b3);
    LAYER(2, W4, b4);
#undef LAYER

    // ---- output layer: o = h@Wo + bo, go = d@Wo (SMEM scalar; small) ----
    float oA0 = bo[0], oA1 = bo[1], oA2 = bo[2], gA0 = 0.f, gA1 = 0.f, gA2 = 0.f;
    float oB0 = bo[0], oB1 = bo[1], oB2 = bo[2], gB0 = 0.f, gB1 = 0.f, gB2 = 0.f;
#pragma unroll
    for (int k = 0; k < 20; ++k) {
        const float hkA = (k & 1) ? HA[k >> 1].y : HA[k >> 1].x;
        const float dkA = (k & 1) ? DA[k >> 1].y : DA[k >> 1].x;
        const float hkB = (k & 1) ? HB[k >> 1].y : HB[k >> 1].x;
        const float dkB = (k & 1) ? DB[k >> 1].y : DB[k >> 1].x;
        const float w0 = Wo[k * 3 + 0];
        const float w1 = Wo[k * 3 + 1];
        const float w2 = Wo[k * 3 + 2];
        oA0 = fmaf(hkA, w0, oA0);  gA0 = fmaf(dkA, w0, gA0);
        oA1 = fmaf(hkA, w1, oA1);  gA1 = fmaf(dkA, w1, gA1);
        oA2 = fmaf(hkA, w2, oA2);  gA2 = fmaf(dkA, w2, gA2);
        oB0 = fmaf(hkB, w0, oB0);  gB0 = fmaf(dkB, w0, gB0);
        oB1 = fmaf(hkB, w1, oB1);  gB1 = fmaf(dkB, w1, gB1);
        oB2 = fmaf(hkB, w2, oB2);  gB2 = fmaf(dkB, w2, gB2);
    }

    const float c1 = C1[0], c2 = C2[0], c3 = C3[0];
    const float fxA = gA0 - c1 * (oA1 - oA0);
    const float fyA = gA1 - oA0 * (c2 - oA2) + oA1;
    const float fzA = gA2 - oA0 * oA1 + c3 * oA2;
    const float fxB = gB0 - c1 * (oB1 - oB0);
    const float fyB = gB1 - oB0 * (c2 - oB2) + oB1;
    const float fzB = gB2 - oB0 * oB1 + c3 * oB2;

    if (p0 + 1 < n) {
        // 12 contiguous floats (48B, 16B-aligned since p0 even) -> 3x dwordx4
        float4* po = reinterpret_cast<float4*>(out + (size_t)p0 * 6);
        po[0] = make_float4(oA0, oA1, oA2, fxA);
        po[1] = make_float4(fyA, fzA, oB0, oB1);
        po[2] = make_float4(oB2, fxB, fyB, fzB);
    } else if (p0 < n) {
        float2* po = reinterpret_cast<float2*>(out + (size_t)p0 * 6);
        po[0] = make_float2(oA0, oA1);
        po[1] = make_float2(oA2, fxA);
        po[2] = make_float2(fyA, fzA);
    }
}

extern "C" void kernel_launch(void* const* d_in, const int* in_sizes, int n_in,
                              void* d_out, int out_size, void* d_ws, size_t ws_size,
                              hipStream_t stream) {
    const float* T  = (const float*)d_in[0];
    const float* W1 = (const float*)d_in[1];
    const float* b1 = (const float*)d_in[2];
    const float* W2 = (const float*)d_in[3];
    const float* b2 = (const float*)d_in[4];
    const float* W3 = (const float*)d_in[5];
    const float* b3 = (const float*)d_in[6];
    const float* W4 = (const float*)d_in[7];
    const float* b4 = (const float*)d_in[8];
    const float* Wo = (const float*)d_in[9];
    const float* bo = (const float*)d_in[10];
    const float* C1 = (const float*)d_in[11];
    const float* C2 = (const float*)d_in[12];
    const float* C3 = (const float*)d_in[13];
    float* out = (float*)d_out;

    const int n = in_sizes[0];
    const int npairs = (n + 1) / 2;
    const int blocks = (npairs + NBLK - 1) / NBLK;
    pinn_kernel<<<blocks, NBLK, 0, stream>>>(T, W1, b1, W2, b2, W3, b3, W4, b4,
                                             Wo, bo, C1, C2, C3, out, n);
}

// Round 21
// 158.010 us; speedup vs baseline: 2.4653x; 2.4653x over previous
//
#include <hip/hip_runtime.h>

#define NBLK 256

typedef float f2 __attribute__((ext_vector_type(2)));   // VGPR pair -> VOP3P v_pk_* f32

static __device__ __forceinline__ f2 pk_fma(f2 a, f2 b, f2 c) {
#if __has_builtin(__builtin_elementwise_fma)
    return __builtin_elementwise_fma(a, b, c);
#else
    f2 r; r.x = fmaf(a.x, b.x, c.x); r.y = fmaf(a.y, b.y, c.y); return r;
#endif
}
static __device__ __forceinline__ f2 splat(float s) { return (f2){s, s}; }

// packed tanh(z) and 1-tanh^2: tanh = 1 - 2/(exp2(2*log2e*z)+1). abs err ~3e-7.
__device__ __forceinline__ void tanh2(const f2 z, f2& th, f2& om) {
    const f2 zz = z * 2.88539008f;
    f2 s;
    s.x = __builtin_amdgcn_rcpf(__builtin_amdgcn_exp2f(zz.x) + 1.0f);
    s.y = __builtin_amdgcn_rcpf(__builtin_amdgcn_exp2f(zz.y) + 1.0f);
    th = 1.0f - 2.0f * s;
    om = 1.0f - th * th;
}

// 2 points per lane, POINT-ACROSS-f2: every f2 = (pointA, pointB) for one feature.
// - multiplier H[k]/D[k] is a ready register pair: zero extraction ops
// - points fused inside each VOP3P: compiler cannot re-split by point (R11's failure)
// - weights enter as SGPR scalar broadcast (1 SGPR/VOP3P, legal)
// amdgpu_waves_per_eu(1,2): raise allocator budget to 512 so the ~190-reg live set
// fits single-pass (R18: launch_bounds(,2) alone -> allocator kept 128 and SPILLED).
__global__ __launch_bounds__(NBLK) __attribute__((amdgpu_waves_per_eu(1, 2)))
void pinn_kernel(
    const float* __restrict__ T,
    const float* __restrict__ W1, const float* __restrict__ b1,
    const float* __restrict__ W2, const float* __restrict__ b2,
    const float* __restrict__ W3, const float* __restrict__ b3,
    const float* __restrict__ W4, const float* __restrict__ b4,
    const float* __restrict__ Wo, const float* __restrict__ bo,
    const float* __restrict__ C1, const float* __restrict__ C2, const float* __restrict__ C3,
    float* __restrict__ out, int n)
{
    const int i0 = blockIdx.x * NBLK + threadIdx.x;
    const int p0 = i0 * 2;
    const int pc = (p0 + 1 < n) ? p0 : (n - 2);     // clamped load base (n >= 2)
    const float2 tt = *reinterpret_cast<const float2*>(T + pc);
    const f2 tp = {tt.x, tt.y};                     // (tA, tB) — lane-local pair

    f2 H[20], D[20];

    // ---- layer 1: z = t*W1 + b1, dz = W1 (tangent dt = 1) ----
#pragma unroll
    for (int j = 0; j < 20; ++j) {
        const float w = W1[j];                      // uniform -> s_load
        f2 th, om;
        tanh2(pk_fma(tp, splat(w), splat(b1[j])), th, om);
        H[j] = th;
        D[j] = om * w;                              // scalar bcast mul
    }

    // ---- layers 2..4: k-outer / j-inner; per (k,j) one SGPR weight feeds 2 pk_fma ----
#pragma unroll 1
    for (int L = 0; L < 3; ++L) {
        const float* __restrict__ WP = (L == 0) ? W2 : (L == 1) ? W3 : W4;
        const float* __restrict__ BP = (L == 0) ? b2 : (L == 1) ? b3 : b4;
        f2 A[20], DD[20];
#pragma unroll
        for (int j = 0; j < 20; ++j) { A[j] = splat(BP[j]); DD[j] = (f2){0.0f, 0.0f}; }
#pragma unroll
        for (int k = 0; k < 20; ++k) {
            const f2 hk = H[k], dk = D[k];          // both points, zero extraction
#pragma unroll
            for (int j = 0; j < 20; ++j) {
                const float w = WP[k * 20 + j];     // uniform row -> s_load_dwordx16
                A[j]  = pk_fma(hk, splat(w), A[j]);
                DD[j] = pk_fma(dk, splat(w), DD[j]);
            }
        }
#pragma unroll
        for (int j = 0; j < 20; ++j) {
            f2 th, om;
            tanh2(A[j], th, om);
            H[j] = th;
            D[j] = om * DD[j];
        }
    }

    // ---- output layer: both points at once in f2 lanes ----
    f2 o0 = splat(bo[0]), o1 = splat(bo[1]), o2 = splat(bo[2]);
    f2 g0 = {0.f, 0.f}, g1 = {0.f, 0.f}, g2 = {0.f, 0.f};
#pragma unroll
    for (int k = 0; k < 20; ++k) {
        const f2 hk = H[k], dk = D[k];
        const float w0 = Wo[k * 3 + 0];
        const float w1 = Wo[k * 3 + 1];
        const float w2 = Wo[k * 3 + 2];
        o0 = pk_fma(hk, splat(w0), o0);  g0 = pk_fma(dk, splat(w0), g0);
        o1 = pk_fma(hk, splat(w1), o1);  g1 = pk_fma(dk, splat(w1), g1);
        o2 = pk_fma(hk, splat(w2), o2);  g2 = pk_fma(dk, splat(w2), g2);
    }

    // Lorenz residuals, elementwise on the point-pair
    const float c1 = C1[0], c2 = C2[0], c3 = C3[0];
    const f2 fx = g0 - c1 * (o1 - o0);
    const f2 fy = g1 - o0 * (c2 - o2) + o1;
    const f2 fz = g2 - o0 * o1 + c3 * o2;

    if (p0 + 1 < n) {
        // 12 contiguous floats (48B, 16B-aligned since p0 even) -> 3x dwordx4
        float4* po = reinterpret_cast<float4*>(out + (size_t)p0 * 6);
        po[0] = make_float4(o0.x, o1.x, o2.x, fx.x);
        po[1] = make_float4(fy.x, fz.x, o0.y, o1.y);
        po[2] = make_float4(o2.y, fx.y, fy.y, fz.y);
    } else if (p0 < n) {
        float2* po = reinterpret_cast<float2*>(out + (size_t)p0 * 6);
        po[0] = make_float2(o0.x, o1.x);
        po[1] = make_float2(o2.x, fx.x);
        po[2] = make_float2(fy.x, fz.x);
    }
}

extern "C" void kernel_launch(void* const* d_in, const int* in_sizes, int n_in,
                              void* d_out, int out_size, void* d_ws, size_t ws_size,
                              hipStream_t stream) {
    const float* T  = (const float*)d_in[0];
    const float* W1 = (const float*)d_in[1];
    const float* b1 = (const float*)d_in[2];
    const float* W2 = (const float*)d_in[3];
    const float* b2 = (const float*)d_in[4];
    const float* W3 = (const float*)d_in[5];
    const float* b3 = (const float*)d_in[6];
    const float* W4 = (const float*)d_in[7];
    const float* b4 = (const float*)d_in[8];
    const float* Wo = (const float*)d_in[9];
    const float* bo = (const float*)d_in[10];
    const float* C1 = (const float*)d_in[11];
    const float* C2 = (const float*)d_in[12];
    const float* C3 = (const float*)d_in[13];
    float* out = (float*)d_out;

    const int n = in_sizes[0];
    const int npairs = (n + 1) / 2;
    const int blocks = (npairs + NBLK - 1) / NBLK;
    pinn_kernel<<<blocks, NBLK, 0, stream>>>(T, W1, b1, W2, b2, W3, b3, W4, b4,
                                             Wo, bo, C1, C2, C3, out, n);
}